// Round 2
// baseline (16471.078 us; speedup 1.0000x reference)
//
#include <hip/hip_runtime.h>

// ---------------------------------------------------------------------------
// GRU: B=32, T=512, D=1024, H=1024.  outputs (B,T,H) + hT (B,H), f32.
// All matmuls: split-bf16 (hi+lo) 3-pass MFMA (f32-level accuracy).
// xp gates z,r -> ws (128 MiB); gate h -> written into d_out (read-once,
// then overwritten by h_t at the same address in the same thread).
// Recurrence: persistent kernel, 64 WGs, U^T fragments pinned in registers,
// cross-WG exchange of h / r*h via LLC with device-scope flag protocol.
// ---------------------------------------------------------------------------

typedef __attribute__((ext_vector_type(8))) short short8;
typedef __attribute__((ext_vector_type(4))) float f32x4;

#define MFMA16(a, b, c) __builtin_amdgcn_mfma_f32_16x16x32_bf16((a), (b), (c), 0, 0, 0)

static constexpr int B_ = 32, T_ = 512, D_ = 1024, H_ = 1024, NG_ = 3072;
static constexpr int M_ = B_ * T_;  // 16384 rows of x / xp

// ---- workspace layout (bytes) ----
static constexpr size_t SZ_WT  = (size_t)NG_ * D_ * 2;   // bf16 transposed W or U
static constexpr size_t SZ_XZR = (size_t)M_ * 2048 * 4;  // f32 xz,xr gates
static constexpr size_t SZ_HV  = (size_t)B_ * H_ * 2;    // bf16 h or rh buffer

static constexpr size_t O_WTHI  = 0;
static constexpr size_t O_WTLO  = O_WTHI + SZ_WT;
static constexpr size_t O_UTHI  = O_WTLO + SZ_WT;
static constexpr size_t O_UTLO  = O_UTHI + SZ_WT;
static constexpr size_t O_XZR   = O_UTLO + SZ_WT;
static constexpr size_t O_BSUM  = O_XZR + SZ_XZR;
static constexpr size_t O_HHI   = O_BSUM + 16384;
static constexpr size_t O_HLO   = O_HHI + SZ_HV;
static constexpr size_t O_RHHI  = O_HLO + SZ_HV;
static constexpr size_t O_RHLO  = O_RHHI + SZ_HV;
static constexpr size_t O_FLAGS = O_RHLO + SZ_HV;
static constexpr size_t WS_NEED = O_FLAGS + 4096;   // ~152.3 MiB

// ---- bf16 helpers (round-to-nearest-even) ----
__device__ inline unsigned short f2bf(float f) {
  unsigned u = __float_as_uint(f);
  u += 0x7FFFu + ((u >> 16) & 1u);
  return (unsigned short)(u >> 16);
}
__device__ inline float bf2f(unsigned short h) {
  return __uint_as_float(((unsigned)h) << 16);
}

// ---------------------------------------------------------------------------
// sentinel: fills out with 0.5f so an insufficient-ws failure is identifiable
// (absmax ~1.5 instead of ~1.0).
// ---------------------------------------------------------------------------
__global__ void k_sentinel(float* __restrict__ out, int n) {
  for (int i = blockIdx.x * 256 + threadIdx.x; i < n; i += gridDim.x * 256)
    out[i] = 0.5f;
}

// ---------------------------------------------------------------------------
// init: h0 -> bf16 pair buffers, zero bsum + flags
// ---------------------------------------------------------------------------
__global__ void k_init(const float* __restrict__ h0,
                       unsigned short* __restrict__ hhi, unsigned short* __restrict__ hlo,
                       float* __restrict__ bsum, unsigned* __restrict__ flags) {
  int i = blockIdx.x * 256 + threadIdx.x;
  if (i < B_ * H_) {
    float v = h0[i];
    unsigned short hi = f2bf(v);
    hhi[i] = hi;
    hlo[i] = f2bf(v - bf2f(hi));
  }
  if (i < NG_) bsum[i] = 0.f;
  if (i < 256) flags[i] = 0u;
}

// ---------------------------------------------------------------------------
// bsum[c] = sum_d b[d][c]   (grid (12,16): 256 cols x 64-row slabs, atomicAdd)
// ---------------------------------------------------------------------------
__global__ void k_bsum(const float* __restrict__ b, float* __restrict__ bsum) {
  int c = blockIdx.x * 256 + threadIdx.x;
  int d0 = blockIdx.y * 64;
  float s = 0.f;
  for (int d = d0; d < d0 + 64; ++d) s += b[(size_t)d * NG_ + c];
  atomicAdd(&bsum[c], s);
}

// ---------------------------------------------------------------------------
// transpose+convert (1024 x 3072) f32 -> (3072 x 1024) bf16 hi/lo; 64x64 tiles
// ---------------------------------------------------------------------------
__global__ void k_trans(const float* __restrict__ in,
                        unsigned short* __restrict__ out_hi, unsigned short* __restrict__ out_lo) {
  __shared__ float s[64][65];
  int d0 = blockIdx.x * 64;
  int n0 = blockIdx.y * 64;
  int t = threadIdx.x;
  int r = t >> 4, c4 = (t & 15) * 4;
  for (int rr = r; rr < 64; rr += 16) {
    float4 v = *(const float4*)&in[(size_t)(d0 + rr) * NG_ + n0 + c4];
    s[rr][c4 + 0] = v.x; s[rr][c4 + 1] = v.y; s[rr][c4 + 2] = v.z; s[rr][c4 + 3] = v.w;
  }
  __syncthreads();
  for (int rr = r; rr < 64; rr += 16) {
    ushort4 hv, lv;
    float v0 = s[c4 + 0][rr], v1 = s[c4 + 1][rr], v2 = s[c4 + 2][rr], v3 = s[c4 + 3][rr];
    hv.x = f2bf(v0); lv.x = f2bf(v0 - bf2f(hv.x));
    hv.y = f2bf(v1); lv.y = f2bf(v1 - bf2f(hv.y));
    hv.z = f2bf(v2); lv.z = f2bf(v2 - bf2f(hv.z));
    hv.w = f2bf(v3); lv.w = f2bf(v3 - bf2f(hv.w));
    size_t o = (size_t)(n0 + rr) * D_ + d0 + c4;
    *(ushort4*)&out_hi[o] = hv;
    *(ushort4*)&out_lo[o] = lv;
  }
}

// ---------------------------------------------------------------------------
// xp = x @ W  via split-bf16 3-pass MFMA.  128x128 tile, BK=32, 4 waves.
// A (x) is staged from f32 with in-kernel hi/lo conversion.
// Cols < 2048 (z,r) -> xzr; cols >= 2048 (h gate) -> xh (the d_out buffer).
// ---------------------------------------------------------------------------
__global__ __launch_bounds__(256, 2) void k_gemm(
    const float* __restrict__ x,
    const unsigned short* __restrict__ wthi, const unsigned short* __restrict__ wtlo,
    float* __restrict__ xzr, float* __restrict__ xh) {
  __shared__ __align__(16) unsigned short Ah[128][40], Al[128][40], Bh[128][40], Bl[128][40];
  const int m0 = blockIdx.x * 128, n0 = blockIdx.y * 128;
  const int tid = threadIdx.x;
  const int wave = tid >> 6, lane = tid & 63;
  const int wr = wave >> 1, wc = wave & 1;
  const int lr = lane & 15, lk = lane >> 4;
  const int sr = tid >> 2, sc = (tid & 3) * 8;      // B staging
  const int asr = tid >> 3, asc = (tid & 7) * 4;    // A staging (f32)

  f32x4 acc[4][4];
#pragma unroll
  for (int i = 0; i < 4; ++i)
#pragma unroll
    for (int j = 0; j < 4; ++j) acc[i][j] = (f32x4){0.f, 0.f, 0.f, 0.f};

#pragma unroll 1
  for (int k0 = 0; k0 < D_; k0 += 32) {
    __syncthreads();
#pragma unroll
    for (int rr = asr; rr < 128; rr += 32) {
      float4 v = *(const float4*)&x[(size_t)(m0 + rr) * D_ + k0 + asc];
      ushort4 h, l;
      h.x = f2bf(v.x); l.x = f2bf(v.x - bf2f(h.x));
      h.y = f2bf(v.y); l.y = f2bf(v.y - bf2f(h.y));
      h.z = f2bf(v.z); l.z = f2bf(v.z - bf2f(h.z));
      h.w = f2bf(v.w); l.w = f2bf(v.w - bf2f(h.w));
      *(ushort4*)&Ah[rr][asc] = h;
      *(ushort4*)&Al[rr][asc] = l;
    }
#pragma unroll
    for (int rr = sr; rr < 128; rr += 64) {
      *(uint4*)&Bh[rr][sc] = *(const uint4*)&wthi[(size_t)(n0 + rr) * D_ + k0 + sc];
      *(uint4*)&Bl[rr][sc] = *(const uint4*)&wtlo[(size_t)(n0 + rr) * D_ + k0 + sc];
    }
    __syncthreads();
    short8 ah[4], al[4], bh[4], bl[4];
#pragma unroll
    for (int f = 0; f < 4; ++f) {
      int ar = wr * 64 + f * 16 + lr;
      int br = wc * 64 + f * 16 + lr;
      ah[f] = *(const short8*)&Ah[ar][lk * 8];
      al[f] = *(const short8*)&Al[ar][lk * 8];
      bh[f] = *(const short8*)&Bh[br][lk * 8];
      bl[f] = *(const short8*)&Bl[br][lk * 8];
    }
#pragma unroll
    for (int i = 0; i < 4; ++i)
#pragma unroll
      for (int j = 0; j < 4; ++j) {
        acc[i][j] = MFMA16(ah[i], bh[j], acc[i][j]);
        acc[i][j] = MFMA16(ah[i], bl[j], acc[i][j]);
        acc[i][j] = MFMA16(al[i], bh[j], acc[i][j]);
      }
  }
#pragma unroll
  for (int i = 0; i < 4; ++i)
#pragma unroll
    for (int j = 0; j < 4; ++j) {
      int row = m0 + wr * 64 + i * 16 + lk * 4;
      int col = n0 + wc * 64 + j * 16 + lr;
#pragma unroll
      for (int rg = 0; rg < 4; ++rg) {
        if (col < 2048)
          xzr[(size_t)(row + rg) * 2048 + col] = acc[i][j][rg];
        else
          xh[(size_t)(row + rg) * H_ + (col - 2048)] = acc[i][j][rg];
      }
    }
}

// ---------------------------------------------------------------------------
// Persistent recurrence. 64 WGs x 256 thr. WG `tile` owns hidden cols
// [tile*16, tile*16+16) of z, r, and h gates. U^T frags live in registers.
// Per step: phase A (z,r; publish rh) -> aflag; phase B (hcand, h) -> bflag.
// xh gate pre-activations live in `outbuf` and are overwritten by h_t.
// ---------------------------------------------------------------------------
__global__ __launch_bounds__(256, 1) void k_recur(
    const float* __restrict__ xzr, const float* __restrict__ bsum,
    const unsigned short* __restrict__ uthi, const unsigned short* __restrict__ utlo,
    const float* __restrict__ h0,
    unsigned short* __restrict__ hhi, unsigned short* __restrict__ hlo,
    unsigned short* __restrict__ rhhi, unsigned short* __restrict__ rhlo,
    unsigned* __restrict__ flags, float* __restrict__ outbuf) {
  const int tile = blockIdx.x;  // 0..63
  const int jc0 = tile * 16;
  const int wave = threadIdx.x >> 6, lane = threadIdx.x & 63;
  const int lr = lane & 15, lk = lane >> 4;

  unsigned* aflag = flags;       // rh/z ready for step t  (value t+1)
  unsigned* bflag = flags + 64;  // h ready for step t     (value t+1)

  // --- persistent U^T fragments: 3 gates x 8 k-chunks (per wave) x hi/lo ---
  short8 uz_h[8], uz_l[8], ur_h[8], ur_l[8], uh_h[8], uh_l[8];
#pragma unroll
  for (int q = 0; q < 8; ++q) {
    int k = (wave * 8 + q) * 32 + lk * 8;
    uz_h[q] = *(const short8*)&uthi[(size_t)(jc0 + lr) * D_ + k];
    uz_l[q] = *(const short8*)&utlo[(size_t)(jc0 + lr) * D_ + k];
    ur_h[q] = *(const short8*)&uthi[(size_t)(1024 + jc0 + lr) * D_ + k];
    ur_l[q] = *(const short8*)&utlo[(size_t)(1024 + jc0 + lr) * D_ + k];
    uh_h[q] = *(const short8*)&uthi[(size_t)(2048 + jc0 + lr) * D_ + k];
    uh_l[q] = *(const short8*)&utlo[(size_t)(2048 + jc0 + lr) * D_ + k];
  }
  float bz = bsum[jc0 + lr];
  float br = bsum[1024 + jc0 + lr];
  float bh_ = bsum[2048 + jc0 + lr];

  // own-column h state in registers (waves 0,1 only; wave = row-tile)
  float h_reg[4], z_reg[4];
#pragma unroll
  for (int rg = 0; rg < 4; ++rg) {
    int b = wave * 16 + lk * 4 + rg;
    h_reg[rg] = (wave < 2) ? h0[(size_t)b * H_ + jc0 + lr] : 0.f;
    z_reg[rg] = 0.f;
  }

  __shared__ __align__(16) float red[4][4][64][4];

#pragma unroll 1
  for (int t = 0; t < T_; ++t) {
    // ================= phase A: z, r =================
    if (threadIdx.x < 64) {
      while (__hip_atomic_load(&bflag[threadIdx.x], __ATOMIC_RELAXED,
                               __HIP_MEMORY_SCOPE_AGENT) < (unsigned)t)
        __builtin_amdgcn_s_sleep(2);
    }
    __syncthreads();
    __threadfence();  // acquire: invalidate stale cache lines
    __syncthreads();

    f32x4 az0 = {0,0,0,0}, az1 = {0,0,0,0}, ar0 = {0,0,0,0}, ar1 = {0,0,0,0};
#pragma unroll
    for (int q = 0; q < 8; ++q) {
      int k = (wave * 8 + q) * 32 + lk * 8;
      short8 a0h = *(const short8*)&hhi[(size_t)lr * H_ + k];
      short8 a0l = *(const short8*)&hlo[(size_t)lr * H_ + k];
      short8 a1h = *(const short8*)&hhi[(size_t)(16 + lr) * H_ + k];
      short8 a1l = *(const short8*)&hlo[(size_t)(16 + lr) * H_ + k];
      az0 = MFMA16(a0h, uz_h[q], az0); az0 = MFMA16(a0h, uz_l[q], az0); az0 = MFMA16(a0l, uz_h[q], az0);
      az1 = MFMA16(a1h, uz_h[q], az1); az1 = MFMA16(a1h, uz_l[q], az1); az1 = MFMA16(a1l, uz_h[q], az1);
      ar0 = MFMA16(a0h, ur_h[q], ar0); ar0 = MFMA16(a0h, ur_l[q], ar0); ar0 = MFMA16(a0l, ur_h[q], ar0);
      ar1 = MFMA16(a1h, ur_h[q], ar1); ar1 = MFMA16(a1h, ur_l[q], ar1); ar1 = MFMA16(a1l, ur_h[q], ar1);
    }
    *(f32x4*)&red[wave][0][lane][0] = az0;
    *(f32x4*)&red[wave][1][lane][0] = az1;
    *(f32x4*)&red[wave][2][lane][0] = ar0;
    *(f32x4*)&red[wave][3][lane][0] = ar1;
    __syncthreads();
    if (wave < 2) {
      f32x4 tz = {0,0,0,0}, tr = {0,0,0,0};
#pragma unroll
      for (int w = 0; w < 4; ++w) {
        tz += *(const f32x4*)&red[w][wave][lane][0];
        tr += *(const f32x4*)&red[w][2 + wave][lane][0];
      }
#pragma unroll
      for (int rg = 0; rg < 4; ++rg) {
        int b = wave * 16 + lk * 4 + rg;
        size_t rowoff = (size_t)(b * T_ + t) * 2048;
        float prez = tz[rg] + xzr[rowoff + jc0 + lr] + bz;
        float prer = tr[rg] + xzr[rowoff + 1024 + jc0 + lr] + br;
        float z = 1.f / (1.f + expf(-prez));
        float r = 1.f / (1.f + expf(-prer));
        z_reg[rg] = z;
        float rh = r * h_reg[rg];
        unsigned short hi = f2bf(rh);
        rhhi[(size_t)b * H_ + jc0 + lr] = hi;
        rhlo[(size_t)b * H_ + jc0 + lr] = f2bf(rh - bf2f(hi));
      }
    }
    __syncthreads();
    if (threadIdx.x == 0)
      __hip_atomic_store(&aflag[tile], (unsigned)(t + 1), __ATOMIC_RELEASE,
                         __HIP_MEMORY_SCOPE_AGENT);

    // ================= phase B: hcand, h update =================
    if (threadIdx.x < 64) {
      while (__hip_atomic_load(&aflag[threadIdx.x], __ATOMIC_RELAXED,
                               __HIP_MEMORY_SCOPE_AGENT) < (unsigned)(t + 1))
        __builtin_amdgcn_s_sleep(2);
    }
    __syncthreads();
    __threadfence();
    __syncthreads();

    f32x4 ch0 = {0,0,0,0}, ch1 = {0,0,0,0};
#pragma unroll
    for (int q = 0; q < 8; ++q) {
      int k = (wave * 8 + q) * 32 + lk * 8;
      short8 a0h = *(const short8*)&rhhi[(size_t)lr * H_ + k];
      short8 a0l = *(const short8*)&rhlo[(size_t)lr * H_ + k];
      short8 a1h = *(const short8*)&rhhi[(size_t)(16 + lr) * H_ + k];
      short8 a1l = *(const short8*)&rhlo[(size_t)(16 + lr) * H_ + k];
      ch0 = MFMA16(a0h, uh_h[q], ch0); ch0 = MFMA16(a0h, uh_l[q], ch0); ch0 = MFMA16(a0l, uh_h[q], ch0);
      ch1 = MFMA16(a1h, uh_h[q], ch1); ch1 = MFMA16(a1h, uh_l[q], ch1); ch1 = MFMA16(a1l, uh_h[q], ch1);
    }
    *(f32x4*)&red[wave][0][lane][0] = ch0;
    *(f32x4*)&red[wave][1][lane][0] = ch1;
    __syncthreads();
    if (wave < 2) {
      f32x4 th = {0,0,0,0};
#pragma unroll
      for (int w = 0; w < 4; ++w) th += *(const f32x4*)&red[w][wave][lane][0];
#pragma unroll
      for (int rg = 0; rg < 4; ++rg) {
        int b = wave * 16 + lk * 4 + rg;
        size_t orow = (size_t)(b * T_ + t) * H_ + jc0 + lr;
        float pre = th[rg] + outbuf[orow] + bh_;   // outbuf holds xh gate
        float hc = tanhf(pre);
        float z = z_reg[rg];
        float hn = z * h_reg[rg] + (1.f - z) * hc;
        h_reg[rg] = hn;
        size_t j = (size_t)b * H_ + jc0 + lr;
        unsigned short hi = f2bf(hn);
        hhi[j] = hi;
        hlo[j] = f2bf(hn - bf2f(hi));
        outbuf[orow] = hn;
        if (t == T_ - 1) outbuf[(size_t)B_ * T_ * H_ + j] = hn;
      }
    }
    __syncthreads();
    if (threadIdx.x == 0)
      __hip_atomic_store(&bflag[tile], (unsigned)(t + 1), __ATOMIC_RELEASE,
                         __HIP_MEMORY_SCOPE_AGENT);
  }
}

// ---------------------------------------------------------------------------
extern "C" void kernel_launch(void* const* d_in, const int* in_sizes, int n_in,
                              void* d_out, int out_size, void* d_ws, size_t ws_size,
                              hipStream_t stream) {
  const float* x  = (const float*)d_in[0];
  const float* W  = (const float*)d_in[1];
  const float* U  = (const float*)d_in[2];
  const float* bb = (const float*)d_in[3];
  const float* h0 = (const float*)d_in[4];
  float* out = (float*)d_out;
  char* ws = (char*)d_ws;

  if (ws_size < WS_NEED) {  // observable failure: out = 0.5 everywhere
    k_sentinel<<<512, 256, 0, stream>>>(out, out_size);
    return;
  }

  unsigned short* wthi = (unsigned short*)(ws + O_WTHI);
  unsigned short* wtlo = (unsigned short*)(ws + O_WTLO);
  unsigned short* uthi = (unsigned short*)(ws + O_UTHI);
  unsigned short* utlo = (unsigned short*)(ws + O_UTLO);
  float*          xzr  = (float*)(ws + O_XZR);
  float*          bsum = (float*)(ws + O_BSUM);
  unsigned short* hhi  = (unsigned short*)(ws + O_HHI);
  unsigned short* hlo  = (unsigned short*)(ws + O_HLO);
  unsigned short* rhhi = (unsigned short*)(ws + O_RHHI);
  unsigned short* rhlo = (unsigned short*)(ws + O_RHLO);
  unsigned*       flags= (unsigned*)(ws + O_FLAGS);

  k_init<<<128, 256, 0, stream>>>(h0, hhi, hlo, bsum, flags);
  k_trans<<<dim3(16, 48), 256, 0, stream>>>(W, wthi, wtlo);
  k_trans<<<dim3(16, 48), 256, 0, stream>>>(U, uthi, utlo);
  k_bsum<<<dim3(12, 16), 256, 0, stream>>>(bb, bsum);
  k_gemm<<<dim3(128, 24), 256, 0, stream>>>(x, wthi, wtlo, xzr, out);
  k_recur<<<64, 256, 0, stream>>>(xzr, bsum, uthi, utlo, h0,
                                  hhi, hlo, rhhi, rhlo, flags, out);
}

// Round 3
// 6352.898 us; speedup vs baseline: 2.5927x; 2.5927x over previous
//
#include <hip/hip_runtime.h>

// ---------------------------------------------------------------------------
// GRU: B=32, T=512, D=1024, H=1024.  outputs (B,T,H) + hT (B,H), f32.
// All matmuls: split-bf16 (hi+lo) 3-pass MFMA (f32-level accuracy).
// xp gates z,r -> ws; gate h -> d_out (read-once then overwritten by h_t).
// Recurrence: persistent kernel, 2 batch-groups x 64 col-tiles (128 WGs).
// Cross-WG h / r*h exchange via LLC using sc0sc1 (write-through / bypass)
// accesses + flag protocol. No threadfence / cache flush on the hot path.
// ---------------------------------------------------------------------------

typedef __attribute__((ext_vector_type(8))) short short8;
typedef __attribute__((ext_vector_type(4))) float f32x4;

#define MFMA16(a, b, c) __builtin_amdgcn_mfma_f32_16x16x32_bf16((a), (b), (c), 0, 0, 0)

static constexpr int B_ = 32, T_ = 512, D_ = 1024, H_ = 1024, NG_ = 3072;
static constexpr int M_ = B_ * T_;

// ---- workspace layout (bytes) ----
static constexpr size_t SZ_WT  = (size_t)NG_ * D_ * 2;   // bf16 transposed W or U
static constexpr size_t SZ_XZR = (size_t)M_ * 2048 * 4;  // f32 xz,xr gates
static constexpr size_t SZ_HV  = (size_t)B_ * H_ * 2;    // bf16 h or rh buffer

static constexpr size_t O_WTHI  = 0;
static constexpr size_t O_WTLO  = O_WTHI + SZ_WT;
static constexpr size_t O_UTHI  = O_WTLO + SZ_WT;
static constexpr size_t O_UTLO  = O_UTHI + SZ_WT;
static constexpr size_t O_XZR   = O_UTLO + SZ_WT;
static constexpr size_t O_BSUM  = O_XZR + SZ_XZR;
static constexpr size_t O_HHI   = O_BSUM + 16384;
static constexpr size_t O_HLO   = O_HHI + SZ_HV;
static constexpr size_t O_RHHI  = O_HLO + SZ_HV;
static constexpr size_t O_RHLO  = O_RHHI + SZ_HV;
static constexpr size_t O_FLAGS = O_RHLO + SZ_HV;
static constexpr size_t WS_NEED = O_FLAGS + 4096;   // ~152.3 MiB

// ---- bf16 helpers (round-to-nearest-even) ----
__device__ inline unsigned short f2bf(float f) {
  unsigned u = __float_as_uint(f);
  u += 0x7FFFu + ((u >> 16) & 1u);
  return (unsigned short)(u >> 16);
}
__device__ inline float bf2f(unsigned short h) {
  return __uint_as_float(((unsigned)h) << 16);
}

// ---- LLC-coherent (sc0 sc1) access helpers ----
__device__ inline short8 ld_cg16(const unsigned short* p) {
  short8 r;
  asm volatile("global_load_dwordx4 %0, %1, off sc0 sc1" : "=v"(r) : "v"(p));
  return r;
}
__device__ inline void st_cg_u16(unsigned short* p, unsigned short v) {
  unsigned vv = v;
  asm volatile("global_store_short %0, %1, off sc0 sc1" :: "v"(p), "v"(vv) : "memory");
}
__device__ inline unsigned ld_cg_u32(const unsigned* p) {
  unsigned r;
  asm volatile("global_load_dword %0, %1, off sc0 sc1\n\ts_waitcnt vmcnt(0)"
               : "=v"(r) : "v"(p) : "memory");
  return r;
}
__device__ inline void st_cg_u32(unsigned* p, unsigned v) {
  asm volatile("global_store_dword %0, %1, off sc0 sc1" :: "v"(p), "v"(v) : "memory");
}
__device__ inline void vmdrain() { asm volatile("s_waitcnt vmcnt(0)" ::: "memory"); }

__device__ inline float sigmoidf_fast(float x) { return 1.f / (1.f + __expf(-x)); }
__device__ inline float tanhf_fast(float x) {
  float e = __expf(2.f * x);          // inf / 0 at extremes -> formula saturates to +-1
  return 1.f - 2.f / (e + 1.f);
}

// ---------------------------------------------------------------------------
__global__ void k_sentinel(float* __restrict__ out, int n) {
  for (int i = blockIdx.x * 256 + threadIdx.x; i < n; i += gridDim.x * 256)
    out[i] = 0.5f;
}

// ---------------------------------------------------------------------------
__global__ void k_init(const float* __restrict__ h0,
                       unsigned short* __restrict__ hhi, unsigned short* __restrict__ hlo,
                       float* __restrict__ bsum, unsigned* __restrict__ flags) {
  int i = blockIdx.x * 256 + threadIdx.x;
  if (i < B_ * H_) {
    float v = h0[i];
    unsigned short hi = f2bf(v);
    hhi[i] = hi;
    hlo[i] = f2bf(v - bf2f(hi));
  }
  if (i < NG_) bsum[i] = 0.f;
  if (i < 256) flags[i] = 0u;
}

// ---------------------------------------------------------------------------
__global__ void k_bsum(const float* __restrict__ b, float* __restrict__ bsum) {
  int c = blockIdx.x * 256 + threadIdx.x;
  int d0 = blockIdx.y * 64;
  float s = 0.f;
  for (int d = d0; d < d0 + 64; ++d) s += b[(size_t)d * NG_ + c];
  atomicAdd(&bsum[c], s);
}

// ---------------------------------------------------------------------------
__global__ void k_trans(const float* __restrict__ in,
                        unsigned short* __restrict__ out_hi, unsigned short* __restrict__ out_lo) {
  __shared__ float s[64][65];
  int d0 = blockIdx.x * 64;
  int n0 = blockIdx.y * 64;
  int t = threadIdx.x;
  int r = t >> 4, c4 = (t & 15) * 4;
  for (int rr = r; rr < 64; rr += 16) {
    float4 v = *(const float4*)&in[(size_t)(d0 + rr) * NG_ + n0 + c4];
    s[rr][c4 + 0] = v.x; s[rr][c4 + 1] = v.y; s[rr][c4 + 2] = v.z; s[rr][c4 + 3] = v.w;
  }
  __syncthreads();
  for (int rr = r; rr < 64; rr += 16) {
    ushort4 hv, lv;
    float v0 = s[c4 + 0][rr], v1 = s[c4 + 1][rr], v2 = s[c4 + 2][rr], v3 = s[c4 + 3][rr];
    hv.x = f2bf(v0); lv.x = f2bf(v0 - bf2f(hv.x));
    hv.y = f2bf(v1); lv.y = f2bf(v1 - bf2f(hv.y));
    hv.z = f2bf(v2); lv.z = f2bf(v2 - bf2f(hv.z));
    hv.w = f2bf(v3); lv.w = f2bf(v3 - bf2f(hv.w));
    size_t o = (size_t)(n0 + rr) * D_ + d0 + c4;
    *(ushort4*)&out_hi[o] = hv;
    *(ushort4*)&out_lo[o] = lv;
  }
}

// ---------------------------------------------------------------------------
// xp = x @ W, split-bf16 3-pass. Cols<2048 -> xzr; cols>=2048 -> xh (d_out).
// ---------------------------------------------------------------------------
__global__ __launch_bounds__(256, 2) void k_gemm(
    const float* __restrict__ x,
    const unsigned short* __restrict__ wthi, const unsigned short* __restrict__ wtlo,
    float* __restrict__ xzr, float* __restrict__ xh) {
  __shared__ __align__(16) unsigned short Ah[128][40], Al[128][40], Bh[128][40], Bl[128][40];
  const int m0 = blockIdx.x * 128, n0 = blockIdx.y * 128;
  const int tid = threadIdx.x;
  const int wave = tid >> 6, lane = tid & 63;
  const int wr = wave >> 1, wc = wave & 1;
  const int lr = lane & 15, lk = lane >> 4;
  const int sr = tid >> 2, sc = (tid & 3) * 8;
  const int asr = tid >> 3, asc = (tid & 7) * 4;

  f32x4 acc[4][4];
#pragma unroll
  for (int i = 0; i < 4; ++i)
#pragma unroll
    for (int j = 0; j < 4; ++j) acc[i][j] = (f32x4){0.f, 0.f, 0.f, 0.f};

#pragma unroll 1
  for (int k0 = 0; k0 < D_; k0 += 32) {
    __syncthreads();
#pragma unroll
    for (int rr = asr; rr < 128; rr += 32) {
      float4 v = *(const float4*)&x[(size_t)(m0 + rr) * D_ + k0 + asc];
      ushort4 h, l;
      h.x = f2bf(v.x); l.x = f2bf(v.x - bf2f(h.x));
      h.y = f2bf(v.y); l.y = f2bf(v.y - bf2f(h.y));
      h.z = f2bf(v.z); l.z = f2bf(v.z - bf2f(h.z));
      h.w = f2bf(v.w); l.w = f2bf(v.w - bf2f(h.w));
      *(ushort4*)&Ah[rr][asc] = h;
      *(ushort4*)&Al[rr][asc] = l;
    }
#pragma unroll
    for (int rr = sr; rr < 128; rr += 64) {
      *(uint4*)&Bh[rr][sc] = *(const uint4*)&wthi[(size_t)(n0 + rr) * D_ + k0 + sc];
      *(uint4*)&Bl[rr][sc] = *(const uint4*)&wtlo[(size_t)(n0 + rr) * D_ + k0 + sc];
    }
    __syncthreads();
    short8 ah[4], al[4], bh[4], bl[4];
#pragma unroll
    for (int f = 0; f < 4; ++f) {
      int ar = wr * 64 + f * 16 + lr;
      int br = wc * 64 + f * 16 + lr;
      ah[f] = *(const short8*)&Ah[ar][lk * 8];
      al[f] = *(const short8*)&Al[ar][lk * 8];
      bh[f] = *(const short8*)&Bh[br][lk * 8];
      bl[f] = *(const short8*)&Bl[br][lk * 8];
    }
#pragma unroll
    for (int i = 0; i < 4; ++i)
#pragma unroll
      for (int j = 0; j < 4; ++j) {
        acc[i][j] = MFMA16(ah[i], bh[j], acc[i][j]);
        acc[i][j] = MFMA16(ah[i], bl[j], acc[i][j]);
        acc[i][j] = MFMA16(al[i], bh[j], acc[i][j]);
      }
  }
#pragma unroll
  for (int i = 0; i < 4; ++i)
#pragma unroll
    for (int j = 0; j < 4; ++j) {
      int row = m0 + wr * 64 + i * 16 + lk * 4;
      int col = n0 + wc * 64 + j * 16 + lr;
#pragma unroll
      for (int rg = 0; rg < 4; ++rg) {
        if (col < 2048)
          xzr[(size_t)(row + rg) * 2048 + col] = acc[i][j][rg];
        else
          xh[(size_t)(row + rg) * H_ + (col - 2048)] = acc[i][j][rg];
      }
    }
}

// ---------------------------------------------------------------------------
// Persistent recurrence. Grid (64,2): 64 col-tiles x 2 batch-groups.
// WG (tile,g) owns hidden cols [tile*16,+16) for batches [g*16,+16).
// Per step: phase A (z,r; publish rh) -> aflag; phase B (hcand, h) -> bflag.
// All cross-WG data via sc0sc1 LLC accesses; flags likewise. No cache flush.
// ---------------------------------------------------------------------------
__global__ __launch_bounds__(256, 1) void k_recur(
    const float* __restrict__ xzr, const float* __restrict__ bsum,
    const unsigned short* __restrict__ uthi, const unsigned short* __restrict__ utlo,
    const float* __restrict__ h0,
    unsigned short* __restrict__ hhi, unsigned short* __restrict__ hlo,
    unsigned short* __restrict__ rhhi, unsigned short* __restrict__ rhlo,
    unsigned* __restrict__ flags, float* __restrict__ outbuf) {
  const int tile = blockIdx.x;       // 0..63
  const int g = blockIdx.y;          // 0..1
  const int jc0 = tile * 16;
  const int brow0 = g * 16;
  const int wave = threadIdx.x >> 6, lane = threadIdx.x & 63;
  const int lr = lane & 15, lk = lane >> 4;

  unsigned* aflag = flags + g * 64;        // rh ready for step t (value t+1)
  unsigned* bflag = flags + 128 + g * 64;  // h ready for step t  (value t+1)

  // --- persistent U^T fragments: 3 gates x 8 k-chunks (per wave) x hi/lo ---
  short8 uz_h[8], uz_l[8], ur_h[8], ur_l[8], uh_h[8], uh_l[8];
#pragma unroll
  for (int q = 0; q < 8; ++q) {
    int k = (wave * 8 + q) * 32 + lk * 8;
    uz_h[q] = *(const short8*)&uthi[(size_t)(jc0 + lr) * D_ + k];
    uz_l[q] = *(const short8*)&utlo[(size_t)(jc0 + lr) * D_ + k];
    ur_h[q] = *(const short8*)&uthi[(size_t)(1024 + jc0 + lr) * D_ + k];
    ur_l[q] = *(const short8*)&utlo[(size_t)(1024 + jc0 + lr) * D_ + k];
    uh_h[q] = *(const short8*)&uthi[(size_t)(2048 + jc0 + lr) * D_ + k];
    uh_l[q] = *(const short8*)&utlo[(size_t)(2048 + jc0 + lr) * D_ + k];
  }
  const float bz = bsum[jc0 + lr];
  const float br = bsum[1024 + jc0 + lr];
  const float bh_ = bsum[2048 + jc0 + lr];

  // wave 0 keeps h,z for rows lk*4+rg; hstate LDS mirror for wave 1 (r*h)
  float h_reg[4], z_reg[4];
  __shared__ float hstate[16][17];
  __shared__ __align__(16) float red[4][2][64][4];

  if (wave == 0) {
#pragma unroll
    for (int rg = 0; rg < 4; ++rg) {
      h_reg[rg] = h0[(size_t)(brow0 + lk * 4 + rg) * H_ + jc0 + lr];
      hstate[lk * 4 + rg][lr] = h_reg[rg];
    }
  }
  __syncthreads();

#pragma unroll 1
  for (int t = 0; t < T_; ++t) {
    // ---- prefetch this step's gate pre-activations (static data) ----
    float xz_pf[4], xr_pf[4], xh_pf[4];
    if (wave == 0) {
#pragma unroll
      for (int rg = 0; rg < 4; ++rg) {
        size_t row = (size_t)(brow0 + lk * 4 + rg) * T_ + t;
        xz_pf[rg] = xzr[row * 2048 + jc0 + lr];
        xh_pf[rg] = outbuf[row * H_ + jc0 + lr];
      }
    } else if (wave == 1) {
#pragma unroll
      for (int rg = 0; rg < 4; ++rg) {
        size_t row = (size_t)(brow0 + lk * 4 + rg) * T_ + t;
        xr_pf[rg] = xzr[row * 2048 + 1024 + jc0 + lr];
      }
    }

    // ================= phase A: z, r =================
    if (threadIdx.x < 64) {
      const unsigned* fp = &bflag[threadIdx.x];
      while (ld_cg_u32(fp) < (unsigned)t) __builtin_amdgcn_s_sleep(1);
    }
    __syncthreads();

    short8 ah[8], al[8];
#pragma unroll
    for (int q = 0; q < 8; ++q) {
      int k = (wave * 8 + q) * 32 + lk * 8;
      ah[q] = ld_cg16(&hhi[(size_t)(brow0 + lr) * H_ + k]);
      al[q] = ld_cg16(&hlo[(size_t)(brow0 + lr) * H_ + k]);
    }
    vmdrain();
    __builtin_amdgcn_sched_barrier(0);

    f32x4 az0 = {0,0,0,0}, az1 = {0,0,0,0}, ar0 = {0,0,0,0}, ar1 = {0,0,0,0};
#pragma unroll
    for (int q = 0; q < 8; q += 2) {
      az0 = MFMA16(ah[q], uz_h[q], az0); az0 = MFMA16(ah[q], uz_l[q], az0); az0 = MFMA16(al[q], uz_h[q], az0);
      ar0 = MFMA16(ah[q], ur_h[q], ar0); ar0 = MFMA16(ah[q], ur_l[q], ar0); ar0 = MFMA16(al[q], ur_h[q], ar0);
      az1 = MFMA16(ah[q+1], uz_h[q+1], az1); az1 = MFMA16(ah[q+1], uz_l[q+1], az1); az1 = MFMA16(al[q+1], uz_h[q+1], az1);
      ar1 = MFMA16(ah[q+1], ur_h[q+1], ar1); ar1 = MFMA16(ah[q+1], ur_l[q+1], ar1); ar1 = MFMA16(al[q+1], ur_h[q+1], ar1);
    }
    az0 += az1; ar0 += ar1;
    *(f32x4*)&red[wave][0][lane][0] = az0;
    *(f32x4*)&red[wave][1][lane][0] = ar0;
    __syncthreads();

    if (wave == 0) {
      f32x4 tz = {0,0,0,0};
#pragma unroll
      for (int w = 0; w < 4; ++w) tz += *(const f32x4*)&red[w][0][lane][0];
#pragma unroll
      for (int rg = 0; rg < 4; ++rg)
        z_reg[rg] = sigmoidf_fast(tz[rg] + xz_pf[rg] + bz);
    } else if (wave == 1) {
      f32x4 tr = {0,0,0,0};
#pragma unroll
      for (int w = 0; w < 4; ++w) tr += *(const f32x4*)&red[w][1][lane][0];
#pragma unroll
      for (int rg = 0; rg < 4; ++rg) {
        float r = sigmoidf_fast(tr[rg] + xr_pf[rg] + br);
        float rh = r * hstate[lk * 4 + rg][lr];
        size_t j = (size_t)(brow0 + lk * 4 + rg) * H_ + jc0 + lr;
        unsigned short hi = f2bf(rh);
        st_cg_u16(&rhhi[j], hi);
        st_cg_u16(&rhlo[j], f2bf(rh - bf2f(hi)));
      }
    }
    vmdrain();
    __syncthreads();
    if (threadIdx.x == 0) st_cg_u32(&aflag[tile], (unsigned)(t + 1));

    // ================= phase B: hcand, h update =================
    if (threadIdx.x < 64) {
      const unsigned* fp = &aflag[threadIdx.x];
      while (ld_cg_u32(fp) < (unsigned)(t + 1)) __builtin_amdgcn_s_sleep(1);
    }
    __syncthreads();

    short8 chq[8], clq[8];
#pragma unroll
    for (int q = 0; q < 8; ++q) {
      int k = (wave * 8 + q) * 32 + lk * 8;
      chq[q] = ld_cg16(&rhhi[(size_t)(brow0 + lr) * H_ + k]);
      clq[q] = ld_cg16(&rhlo[(size_t)(brow0 + lr) * H_ + k]);
    }
    vmdrain();
    __builtin_amdgcn_sched_barrier(0);

    f32x4 ch0 = {0,0,0,0}, ch1 = {0,0,0,0};
#pragma unroll
    for (int q = 0; q < 8; q += 2) {
      ch0 = MFMA16(chq[q], uh_h[q], ch0); ch0 = MFMA16(chq[q], uh_l[q], ch0); ch0 = MFMA16(clq[q], uh_h[q], ch0);
      ch1 = MFMA16(chq[q+1], uh_h[q+1], ch1); ch1 = MFMA16(chq[q+1], uh_l[q+1], ch1); ch1 = MFMA16(clq[q+1], uh_h[q+1], ch1);
    }
    ch0 += ch1;
    *(f32x4*)&red[wave][0][lane][0] = ch0;
    __syncthreads();

    if (wave == 0) {
      f32x4 th = {0,0,0,0};
#pragma unroll
      for (int w = 0; w < 4; ++w) th += *(const f32x4*)&red[w][0][lane][0];
#pragma unroll
      for (int rg = 0; rg < 4; ++rg) {
        float hc = tanhf_fast(th[rg] + xh_pf[rg] + bh_);
        float z = z_reg[rg];
        float hn = z * h_reg[rg] + (1.f - z) * hc;
        h_reg[rg] = hn;
        hstate[lk * 4 + rg][lr] = hn;
        size_t row = (size_t)(brow0 + lk * 4 + rg) * T_ + t;
        outbuf[row * H_ + jc0 + lr] = hn;
        size_t j = (size_t)(brow0 + lk * 4 + rg) * H_ + jc0 + lr;
        unsigned short hi = f2bf(hn);
        st_cg_u16(&hhi[j], hi);
        st_cg_u16(&hlo[j], f2bf(hn - bf2f(hi)));
        if (t == T_ - 1) outbuf[(size_t)B_ * T_ * H_ + j] = hn;
      }
    }
    vmdrain();
    __syncthreads();
    if (threadIdx.x == 0) st_cg_u32(&bflag[tile], (unsigned)(t + 1));
  }
}

// ---------------------------------------------------------------------------
extern "C" void kernel_launch(void* const* d_in, const int* in_sizes, int n_in,
                              void* d_out, int out_size, void* d_ws, size_t ws_size,
                              hipStream_t stream) {
  const float* x  = (const float*)d_in[0];
  const float* W  = (const float*)d_in[1];
  const float* U  = (const float*)d_in[2];
  const float* bb = (const float*)d_in[3];
  const float* h0 = (const float*)d_in[4];
  float* out = (float*)d_out;
  char* ws = (char*)d_ws;

  if (ws_size < WS_NEED) {  // observable failure: out = 0.5 everywhere
    k_sentinel<<<512, 256, 0, stream>>>(out, out_size);
    return;
  }

  unsigned short* wthi = (unsigned short*)(ws + O_WTHI);
  unsigned short* wtlo = (unsigned short*)(ws + O_WTLO);
  unsigned short* uthi = (unsigned short*)(ws + O_UTHI);
  unsigned short* utlo = (unsigned short*)(ws + O_UTLO);
  float*          xzr  = (float*)(ws + O_XZR);
  float*          bsum = (float*)(ws + O_BSUM);
  unsigned short* hhi  = (unsigned short*)(ws + O_HHI);
  unsigned short* hlo  = (unsigned short*)(ws + O_HLO);
  unsigned short* rhhi = (unsigned short*)(ws + O_RHHI);
  unsigned short* rhlo = (unsigned short*)(ws + O_RHLO);
  unsigned*       flags= (unsigned*)(ws + O_FLAGS);

  k_init<<<128, 256, 0, stream>>>(h0, hhi, hlo, bsum, flags);
  k_trans<<<dim3(16, 48), 256, 0, stream>>>(W, wthi, wtlo);
  k_trans<<<dim3(16, 48), 256, 0, stream>>>(U, uthi, utlo);
  k_bsum<<<dim3(12, 16), 256, 0, stream>>>(bb, bsum);
  k_gemm<<<dim3(128, 24), 256, 0, stream>>>(x, wthi, wtlo, xzr, out);
  k_recur<<<dim3(64, 2), 256, 0, stream>>>(xzr, bsum, uthi, utlo, h0,
                                           hhi, hlo, rhhi, rhlo, flags, out);
}